// Round 16
// baseline (468.649 us; speedup 1.0000x reference)
//
#include <hip/hip_runtime.h>
#include <hip/hip_fp16.h>

// DKVMN forward, v16 — evict SMEM from the state loop (stall theory).
//  R15 calibration: state issue 249us (~373cyc/step) == VALU floor for 150
//  FMA-equiv/col-step with 4-cyc VOP3P (fdot2 & hfma2 both half-rate). The
//  remaining ~78us is all-wave stall. Root cause theory: per-step wrow s_load
//  is SMEM; SMEM completes OUT-OF-ORDER so any lgkmcnt(0) drains prefetches
//  too — SMEM prefetch is structurally impossible (explains R7/R11 nulls).
//  v16: w rows via VGPR ping-pong global_load (vmcnt, in-flight prefetch OK),
//  q/qa indices staged in LDS once (DS in-order, fine lgkm waits). Zero SMEM
//  in the loop. Cost: VGPR ~90 -> 5 waves/SIMD (was 8) — issue-bound, OK.
//  k1 prep : EA {-e,a} f16 | Wt/Wh/Q1 | W1s pack | zero outputs 1..3.
//  k2 dkvmn_state: barrier-1, 256 thr, fdot2+hfma2, VGPR w ping-pong.
//  k3 mlp_pred : MFMA 16x16x32 bf16 GEMM [B*S,224]@[224,64] + fused epilogue.
// Workspace: Wt 1MB | Q1 1MB | EA 8MB | W1s 32KB | Wh 0.6MB | RD 164MB.

#define NQ1   5001
#define NQA   10001
#define MEMN  50
#define KD    50
#define VD    200
#define FC    50
#define BB    2048
#define SS    200
#define EA_R  16
#define WHS   28       // Wh row stride in u32 (25 pairs + 3 pad, 112B, 16B-aligned)

#define EA_B   626     // ceil(10001/16)
#define WQ_B   1251    // ceil(5001/4)
#define PACK_B 8
#define PREP_G (EA_B + WQ_B + PACK_B)   // 1885 blocks

typedef unsigned int   u32;
typedef unsigned short u16;
typedef short    s8v __attribute__((ext_vector_type(8)));   // 8 bf16 (4 VGPRs)
typedef float    f4v __attribute__((ext_vector_type(4)));   // MFMA C/D
typedef _Float16 h2v __attribute__((ext_vector_type(2)));   // packed f16 pair
typedef u32      u4v __attribute__((ext_vector_type(4)));   // 16B load

__device__ __forceinline__ float fast_sigmoid(float x) { return 1.f / (1.f + __expf(-x)); }
__device__ __forceinline__ float fast_tanh(float x) {
    float e2 = __expf(2.f * x);           // inf-safe
    return 1.f - 2.f / (e2 + 1.f);
}
__device__ __forceinline__ float bfu16_to_f(u16 u) {
    union { float f; u32 i; } x; x.i = ((u32)u) << 16; return x.f;
}
__device__ __forceinline__ u16 f_to_bfu16(float f) {   // RNE, finite inputs
    union { float f; u32 i; } x; x.f = f;
    return (u16)((x.i + 0x7fffu + ((x.i >> 16) & 1u)) >> 16);
}
__device__ __forceinline__ h2v u32_to_h2v(u32 u) {
    union { u32 i; h2v h; } x; x.i = u; return x.h;
}
__device__ __forceinline__ u16 f16bits(float f) {
    union { __half h; u16 u; } x; x.h = __float2half(f); return x.u;
}
__device__ __forceinline__ float h16_to_f(u16 u) {
    union { u16 u; __half h; } x; x.u = u; return __half2float(x.h);
}

// ---- merged prep: EA table | per-q tables | W1 pack | aux-output zeroing ----
__global__ __launch_bounds__(256) void prep(
        const float* __restrict__ qemb, const float* __restrict__ km,
        const float* __restrict__ w1,   const float* __restrict__ b1,
        const float* __restrict__ qaemb,
        const float* __restrict__ ew,   const float* __restrict__ ebias,
        const float* __restrict__ aw,   const float* __restrict__ abias,
        float* __restrict__ Wt, u32* __restrict__ Wh, float* __restrict__ Q1,
        u32* __restrict__ EA, u16* __restrict__ W1s,
        float* __restrict__ out_aux) {
    const int tid = threadIdx.x;
    const int blk = blockIdx.x;

    // every block zeroes its slice of outputs 1..3 (replaces hipMemsetAsync)
    for (size_t i = (size_t)blk * 256 + tid; i < 3ull * BB * SS;
         i += (size_t)PREP_G * 256)
        out_aux[i] = 0.f;

    __shared__ float smem[VD * EA_R];             // 12.8 KB (EA role); WQ uses 256

    if (blk < EA_B) {
        // ---------------- EA role: {-e, a} packed f16 ----------------
        const int r0 = blk * EA_R;
        if (tid < VD) {
            #pragma unroll
            for (int r = 0; r < EA_R; ++r) {
                int row = r0 + r;
                smem[tid * EA_R + r] = (row < NQA) ? qaemb[(size_t)row * VD + tid] : 0.f;
            }
        }
        __syncthreads();
        if (tid >= VD) return;

        float accE[EA_R], accA[EA_R];
        #pragma unroll
        for (int r = 0; r < EA_R; ++r) { accE[r] = 0.f; accA[r] = 0.f; }
        for (int k = 0; k < VD; ++k) {
            float we = ew[k * VD + tid];
            float wa = aw[k * VD + tid];
            #pragma unroll
            for (int r = 0; r < EA_R; ++r) {
                float qv = smem[k * EA_R + r];
                accE[r] = fmaf(qv, we, accE[r]);
                accA[r] = fmaf(qv, wa, accA[r]);
            }
        }
        float be = ebias[tid], ba = abias[tid];
        #pragma unroll
        for (int r = 0; r < EA_R; ++r) {
            int row = r0 + r;
            if (row < NQA) {
                u16 ne16 = f16bits(-fast_sigmoid(accE[r] + be));   // -e
                u16 a16  = f16bits(fast_tanh(accA[r] + ba));       //  a
                EA[(size_t)row * VD + tid] = (u32)ne16 | ((u32)a16 << 16);
            }
        }
    } else if (blk < EA_B + WQ_B) {
        // ---------------- WQ role (proven build_wq, 4 q/block) ----------------
        const int lane = tid & 63;
        const int wv   = tid >> 6;
        const int q    = (blk - EA_B) * 4 + wv;
        const bool qok = q < NQ1;
        float* qrow = smem + wv * 64;             // 50 used per wave
        if (qok && lane < KD) qrow[lane] = qemb[q * KD + lane];
        __syncthreads();
        if (!qok) return;

        float s = -1e30f;
        if (lane < MEMN) {
            s = 0.f;
            #pragma unroll
            for (int k = 0; k < KD; ++k) s = fmaf(qrow[k], km[lane * KD + k], s);
        }
        float mx = s;
        #pragma unroll
        for (int off = 32; off >= 1; off >>= 1) mx = fmaxf(mx, __shfl_xor(mx, off, 64));
        float e = (lane < MEMN) ? __expf(s - mx) : 0.f;
        float sum = e;
        #pragma unroll
        for (int off = 32; off >= 1; off >>= 1) sum += __shfl_xor(sum, off, 64);
        float wv_ = (lane < MEMN) ? (e / sum) : 0.f;
        if (lane < MEMN) Wt[q * MEMN + lane] = wv_;

        // f16-pair row: lane i<25 packs (w[2i], w[2i+1])
        float plo = __shfl(wv_, 2 * (lane & 31), 64);
        float phi = __shfl(wv_, 2 * (lane & 31) + 1, 64);
        if (lane < 25) {
            Wh[q * WHS + lane] = (u32)f16bits(plo) | ((u32)f16bits(phi) << 16);
        } else if (lane < WHS) {
            Wh[q * WHS + lane] = 0;
        }

        if (lane < FC) {
            float h = b1[lane];
            #pragma unroll
            for (int k = 0; k < KD; ++k)
                h = fmaf(qrow[k], w1[(VD + k) * FC + lane], h);
            Q1[q * FC + lane] = h;
        }
    } else {
        // ---------------- pack role (proven pack_w1) ----------------
        for (int idx = (blk - EA_B - WQ_B) * 256 + tid; idx < 4 * 7 * 64 * 8;
             idx += PACK_B * 256) {
            int j    = idx & 7;
            int lane = (idx >> 3) & 63;
            int kt   = (idx >> 9) % 7;
            int nt   = idx / 3584;
            int k = kt * 32 + ((lane >> 4) << 3) + j;
            int n = nt * 16 + (lane & 15);
            float v = (k < VD && n < FC) ? w1[k * FC + n] : 0.f;
            W1s[idx] = f_to_bfu16(v);
        }
    }
}

// ---- recurrence: zero SMEM in loop; VGPR w ping-pong; LDS indices ----
__global__ __launch_bounds__(256) void dkvmn_state(
        const int* __restrict__ qd, const int* __restrict__ qad,
        const u32* __restrict__ Wh, const u32* __restrict__ EA,
        const float* __restrict__ ivm, u16* __restrict__ READ) {
    const int tid = threadIdx.x;
    const int b   = blockIdx.x;
    const int v   = tid;                         // 0..255, active if < VD
    const bool active = v < VD;
    const int vc = active ? v : VD - 1;

    __shared__ int qs_l[SS];                     // 1.6 KB total
    __shared__ int qas_l[SS];
    const int base = b * SS;
    if (tid < SS) {
        qs_l[tid]  = qd[base + tid];
        qas_l[tid] = qad[base + tid];
    }

    h2v mv[25];                                  // pair i = slots (2i, 2i+1)
    #pragma unroll
    for (int i = 0; i < 25; ++i) {
        mv[i].x = (_Float16)ivm[(2 * i) * VD + vc];
        mv[i].y = (_Float16)ivm[(2 * i + 1) * VD + vc];
    }
    __syncthreads();                             // indices staged (only barrier)

    // w ping-pong: 7x dwordx4 per row (WHS=28 u32, rows 16B-aligned, pad=0)
    u4v wA[7], wB[7];
    {
        const u4v* w0 = (const u4v*)(Wh + (size_t)qs_l[0] * WHS);
        const u4v* w1p = (const u4v*)(Wh + (size_t)qs_l[1] * WHS);
        #pragma unroll
        for (int i = 0; i < 7; ++i) wA[i] = w0[i];
        #pragma unroll
        for (int i = 0; i < 7; ++i) wB[i] = w1p[i];
    }
    u32 ea_c = EA[(size_t)qas_l[0] * VD + vc];
    u32 ea_n = EA[(size_t)qas_l[1] * VD + vc];

    #define DK_COMPUTE(tc, WCUR, WOTH)                                         \
    {                                                                          \
        /* EA prefetch for (tc)+2 (clamped) */                                 \
        int tn = (tc) + 2; tn = (tn < SS) ? tn : (SS - 1);                     \
        u32 ea_nn = EA[(size_t)qas_l[tn] * VD + vc];                           \
        h2v nev2 = u32_to_h2v(__builtin_amdgcn_perm(ea_c, ea_c, 0x01000100u)); \
        h2v av2  = u32_to_h2v(__builtin_amdgcn_perm(ea_c, ea_c, 0x03020302u)); \
        float rdA = 0.f, rdB = 0.f;                                            \
        _Pragma("unroll")                                                      \
        for (int i = 0; i < 25; ++i) {                                         \
            h2v wp = u32_to_h2v(WCUR[i >> 2][i & 3]);                          \
            if (i & 1) {                                                       \
                rdB = __builtin_amdgcn_fdot2(wp, mv[i], rdB, false);           \
            } else {                                                           \
                rdA = __builtin_amdgcn_fdot2(wp, mv[i], rdA, false);           \
            }                                                                  \
            mv[i] = __builtin_elementwise_fma(                                 \
                wp, __builtin_elementwise_fma(nev2, mv[i], av2), mv[i]);       \
        }                                                                      \
        if (active)                                                            \
            READ[(size_t)(base + (tc)) * VD + v] = f_to_bfu16(rdA + rdB);      \
        ea_c = ea_n; ea_n = ea_nn;                                             \
        /* refill the buffer just retired (used again at (tc)+2) */            \
        const u4v* wrn = (const u4v*)(Wh + (size_t)qs_l[tn] * WHS);            \
        _Pragma("unroll")                                                      \
        for (int i = 0; i < 7; ++i) WOTH[i] = wrn[i];                          \
    }

    for (int t = 0; t < SS; t += 2) {
        DK_COMPUTE(t,     wA, wA);   // wA consumed, refill wA for t+2
        DK_COMPUTE(t + 1, wB, wB);   // wB consumed, refill wB for t+3
    }
    #undef DK_COMPUTE
}

// ---- prediction MLP via MFMA: per wave one 16-row strip, K=224, N=64 ----
__global__ __launch_bounds__(256) void mlp_pred(
        const u16* __restrict__ RD, const int* __restrict__ qd,
        const float* __restrict__ Q1tab, const u16* __restrict__ W1s,
        const float* __restrict__ w2, const float* __restrict__ b2,
        float* __restrict__ out) {
    const int tid  = threadIdx.x;
    const int lane = tid & 63;
    const int wv   = tid >> 6;
    const int strip = blockIdx.x * 4 + wv;
    const int row0  = strip * 16;

    const int mrow = lane & 15;        // A row within strip / C-D col (feature)
    const int quad = lane >> 4;

    s8v a[7];
    {
        const u16* arow = RD + (size_t)(row0 + mrow) * VD + quad * 8;
        #pragma unroll
        for (int kt = 0; kt < 7; ++kt)
            a[kt] = *(const s8v*)(arow + kt * 32);   // k>=200 garbage * B=0
    }

    const float b2f = b2[0];
    float pf[4] = {0.f, 0.f, 0.f, 0.f};

    #pragma unroll
    for (int nt = 0; nt < 4; ++nt) {
        s8v bfr[7];
        #pragma unroll
        for (int kt = 0; kt < 7; ++kt)
            bfr[kt] = *(const s8v*)(W1s + (((nt * 7 + kt) * 64) + lane) * 8);

        f4v acc = {0.f, 0.f, 0.f, 0.f};
        #pragma unroll
        for (int kt = 0; kt < 7; ++kt)
            acc = __builtin_amdgcn_mfma_f32_16x16x32_bf16(a[kt], bfr[kt], acc, 0, 0, 0);

        const int f = nt * 16 + mrow;                  // output feature col
        const float w2f = (f < FC) ? w2[f] : 0.f;
        #pragma unroll
        for (int r = 0; r < 4; ++r) {
            int row = row0 + quad * 4 + r;
            float h = acc[r] + Q1tab[qd[row] * FC + f];
            pf[r] = fmaf(fast_tanh(h), w2f, pf[r]);
        }
    }

    #pragma unroll
    for (int r = 0; r < 4; ++r) {
        float s = pf[r];
        s += __shfl_xor(s, 1, 64);
        s += __shfl_xor(s, 2, 64);
        s += __shfl_xor(s, 4, 64);
        s += __shfl_xor(s, 8, 64);
        if (mrow == 0)
            out[row0 + quad * 4 + r] = fast_sigmoid(s + b2f);
    }
}

// ---- fallback (barrier version, f32) if workspace too small ----
__global__ void dkvmn_main(const int* __restrict__ qd, const int* __restrict__ qad,
                           const float* __restrict__ Wtab, const float* __restrict__ Q1tab,
                           const u32* __restrict__ EA,
                           const float* __restrict__ ivm,
                           const float* __restrict__ w1,
                           const float* __restrict__ w2,
                           const float* __restrict__ b2,
                           float* __restrict__ out) {
    const int tid  = threadIdx.x;
    const int b    = blockIdx.x;
    const int v    = tid;
    const int lane = tid & 63;
    const int wv   = tid >> 6;

    __shared__ alignas(16) float read_lds[4 * 52];
    __shared__ alignas(16) float part_lds[4 * 52];

    float mv[MEMN];
    if (v < VD) {
        #pragma unroll
        for (int m = 0; m < MEMN; ++m) mv[m] = ivm[m * VD + v];
    }
    float w1r[50];
    if (lane < FC) {
        #pragma unroll
        for (int i = 0; i < 50; ++i) w1r[i] = w1[(wv * 50 + i) * FC + lane];
    } else {
        #pragma unroll
        for (int i = 0; i < 50; ++i) w1r[i] = 0.f;
    }
    const float w2f = (tid < FC) ? w2[tid] : 0.f;
    const float b2f = b2[0];

    const int* qrow_i  = qd  + b * SS;
    const int* qarow_i = qad + b * SS;
    const int jchunk = v / 50;
    const int wslot  = jchunk * 52 + (v - jchunk * 50);

    for (int t = 0; t < SS; ++t) {
        const int q  = __builtin_amdgcn_readfirstlane(qrow_i[t]);
        const int qa = __builtin_amdgcn_readfirstlane(qarow_i[t]);
        const float* wrow = Wtab + q * MEMN;

        u32 ea = 0;
        if (v < VD) ea = EA[(size_t)qa * VD + v];
        float ne = h16_to_f((u16)(ea & 0xffffu));   // -e
        float av = h16_to_f((u16)(ea >> 16));       //  a

        if (v < VD) {
            float rd0 = 0.f, rd1 = 0.f;
            #pragma unroll
            for (int m = 0; m < MEMN; m += 2) {
                float wm0 = wrow[m], wm1 = wrow[m + 1];
                rd0 = fmaf(wm0, mv[m], rd0);
                mv[m] = fmaf(wm0, fmaf(ne, mv[m], av), mv[m]);
                rd1 = fmaf(wm1, mv[m + 1], rd1);
                mv[m + 1] = fmaf(wm1, fmaf(ne, mv[m + 1], av), mv[m + 1]);
            }
            read_lds[wslot] = rd0 + rd1;
        }
        __syncthreads();

        float part = 0.f;
        {
            const float* rlc = read_lds + wv * 52;
            #pragma unroll
            for (int i = 0; i < 48; i += 4) {
                float4 x = *(const float4*)(rlc + i);
                part = fmaf(x.x, w1r[i],     part);
                part = fmaf(x.y, w1r[i + 1], part);
                part = fmaf(x.z, w1r[i + 2], part);
                part = fmaf(x.w, w1r[i + 3], part);
            }
            part = fmaf(rlc[48], w1r[48], part);
            part = fmaf(rlc[49], w1r[49], part);
        }
        if (lane < FC) part_lds[wv * 52 + lane] = part;
        __syncthreads();

        if (wv == 0) {
            float pf = 0.f;
            if (lane < FC) {
                float h = part_lds[lane] + part_lds[52 + lane] +
                          part_lds[104 + lane] + part_lds[156 + lane] +
                          Q1tab[q * FC + lane];
                pf = fast_tanh(h) * w2f;
            }
            #pragma unroll
            for (int off = 32; off >= 1; off >>= 1) pf += __shfl_xor(pf, off, 64);
            if (lane == 0) out[b * SS + t] = fast_sigmoid(pf + b2f);
        }
    }
}

extern "C" void kernel_launch(void* const* d_in, const int* in_sizes, int n_in,
                              void* d_out, int out_size, void* d_ws, size_t ws_size,
                              hipStream_t stream) {
    const int* qd  = (const int*)d_in[0];
    const int* qad = (const int*)d_in[1];
    const float* qemb  = (const float*)d_in[2];
    const float* qaemb = (const float*)d_in[3];
    const float* km    = (const float*)d_in[4];
    const float* ivm   = (const float*)d_in[5];
    const float* ew    = (const float*)d_in[6];
    const float* eb    = (const float*)d_in[7];
    const float* aw    = (const float*)d_in[8];
    const float* ab    = (const float*)d_in[9];
    const float* w1    = (const float*)d_in[10];
    const float* b1    = (const float*)d_in[11];
    const float* w2    = (const float*)d_in[12];
    const float* b2    = (const float*)d_in[13];
    float* out = (float*)d_out;
    (void)in_sizes; (void)n_in; (void)out_size;

    char* ws = (char*)d_ws;
    float* Wt  = (float*)(ws);                       // 1,000,200 -> pad 1,000,448
    float* Q1  = (float*)(ws + 1000448);             // 1,000,200 -> pad 1,000,448
    u32*   EA  = (u32*)  (ws + 2000896);             // 8,000,800 -> pad 8,001,024
    u16*   W1s = (u16*)  (ws + 10001920);            // 28,672    -> pad 32,768
    u32*   Wh  = (u32*)  (ws + 10034688);            // 560,112   -> pad 560,640
    u16*   RD  = (u16*)  (ws + 10595328);            // 163,840,000
    const size_t need = 10595328ull + 163840000ull + 512ull;

    // prep: EA + Wt/Wh/Q1 + W1s + zero outputs 1..3 (one dispatch)
    prep<<<PREP_G, 256, 0, stream>>>(qemb, km, w1, b1, qaemb, ew, eb, aw, ab,
                                     Wt, Wh, Q1, EA, W1s, out + (size_t)BB * SS);

    if (ws_size >= need) {
        dkvmn_state<<<BB, 256, 0, stream>>>(qd, qad, Wh, EA, ivm, RD);
        mlp_pred<<<(BB * SS) / 64, 256, 0, stream>>>(RD, qd, Q1, W1s, w2, b2, out);
    } else {
        dkvmn_main<<<BB, 256, 0, stream>>>(qd, qad, Wt, Q1, EA, ivm, w1, w2, b2, out);
    }
}

// Round 17
// 459.205 us; speedup vs baseline: 1.0206x; 1.0206x over previous
//
#include <hip/hip_runtime.h>
#include <hip/hip_fp16.h>

// DKVMN forward, v17 == exact R15 (the measured best: 462.4us total).
//  R16 (SMEM eviction via VGPR w ping-pong) regressed issue 249->267us —
//  VMEM broadcast refills cost more slots than the SMEM drain they removed.
//  Final ledger: state issue floor ~250us (VOP3P/fdot2 measured 4-cyc, no
//  packed 2x: R6/R12/R13/R15); stall ~75us immune to LDS staging (R7),
//  prefetch depth (R11), SMEM eviction (R16); fusion hurts via VGPR (R10);
//  prep consolidation captured (R14). This is the structural plateau.
//  k1 prep : EA {-e,a} f16 | Wt/Wh/Q1 | W1s pack | zero outputs 1..3.
//  k2 dkvmn_state: barrier-free, 256 thr, fdot2 read + hfma2 update, SGPR Wh
//      pairs, EA depth-2 prefetch, RD bf16.
//  k3 mlp_pred : MFMA 16x16x32 bf16 GEMM [B*S,224]@[224,64] + fused epilogue.
// Workspace: Wt 1MB | Q1 1MB | EA 8MB | W1s 32KB | Wh 0.6MB | RD 164MB.

#define NQ1   5001
#define NQA   10001
#define MEMN  50
#define KD    50
#define VD    200
#define FC    50
#define BB    2048
#define SS    200
#define EA_R  16
#define WHS   28       // Wh row stride in u32 (25 pairs + 3 pad, 112B)

#define EA_B   626     // ceil(10001/16)
#define WQ_B   1251    // ceil(5001/4)
#define PACK_B 8
#define PREP_G (EA_B + WQ_B + PACK_B)   // 1885 blocks

typedef unsigned int   u32;
typedef unsigned short u16;
typedef short    s8v __attribute__((ext_vector_type(8)));   // 8 bf16 (4 VGPRs)
typedef float    f4v __attribute__((ext_vector_type(4)));   // MFMA C/D
typedef _Float16 h2v __attribute__((ext_vector_type(2)));   // packed f16 pair

__device__ __forceinline__ float fast_sigmoid(float x) { return 1.f / (1.f + __expf(-x)); }
__device__ __forceinline__ float fast_tanh(float x) {
    float e2 = __expf(2.f * x);           // inf-safe
    return 1.f - 2.f / (e2 + 1.f);
}
__device__ __forceinline__ float bfu16_to_f(u16 u) {
    union { float f; u32 i; } x; x.i = ((u32)u) << 16; return x.f;
}
__device__ __forceinline__ u16 f_to_bfu16(float f) {   // RNE, finite inputs
    union { float f; u32 i; } x; x.f = f;
    return (u16)((x.i + 0x7fffu + ((x.i >> 16) & 1u)) >> 16);
}
__device__ __forceinline__ h2v u32_to_h2v(u32 u) {
    union { u32 i; h2v h; } x; x.i = u; return x.h;
}
__device__ __forceinline__ u16 f16bits(float f) {
    union { __half h; u16 u; } x; x.h = __float2half(f); return x.u;
}
__device__ __forceinline__ float h16_to_f(u16 u) {
    union { u16 u; __half h; } x; x.u = u; return __half2float(x.h);
}

// ---- merged prep: EA table | per-q tables | W1 pack | aux-output zeroing ----
__global__ __launch_bounds__(256) void prep(
        const float* __restrict__ qemb, const float* __restrict__ km,
        const float* __restrict__ w1,   const float* __restrict__ b1,
        const float* __restrict__ qaemb,
        const float* __restrict__ ew,   const float* __restrict__ ebias,
        const float* __restrict__ aw,   const float* __restrict__ abias,
        float* __restrict__ Wt, u32* __restrict__ Wh, float* __restrict__ Q1,
        u32* __restrict__ EA, u16* __restrict__ W1s,
        float* __restrict__ out_aux) {
    const int tid = threadIdx.x;
    const int blk = blockIdx.x;

    // every block zeroes its slice of outputs 1..3 (replaces hipMemsetAsync)
    for (size_t i = (size_t)blk * 256 + tid; i < 3ull * BB * SS;
         i += (size_t)PREP_G * 256)
        out_aux[i] = 0.f;

    __shared__ float smem[VD * EA_R];             // 12.8 KB (EA role); WQ uses 256

    if (blk < EA_B) {
        // ---------------- EA role: {-e, a} packed f16 ----------------
        const int r0 = blk * EA_R;
        if (tid < VD) {
            #pragma unroll
            for (int r = 0; r < EA_R; ++r) {
                int row = r0 + r;
                smem[tid * EA_R + r] = (row < NQA) ? qaemb[(size_t)row * VD + tid] : 0.f;
            }
        }
        __syncthreads();
        if (tid >= VD) return;

        float accE[EA_R], accA[EA_R];
        #pragma unroll
        for (int r = 0; r < EA_R; ++r) { accE[r] = 0.f; accA[r] = 0.f; }
        for (int k = 0; k < VD; ++k) {
            float we = ew[k * VD + tid];
            float wa = aw[k * VD + tid];
            #pragma unroll
            for (int r = 0; r < EA_R; ++r) {
                float qv = smem[k * EA_R + r];
                accE[r] = fmaf(qv, we, accE[r]);
                accA[r] = fmaf(qv, wa, accA[r]);
            }
        }
        float be = ebias[tid], ba = abias[tid];
        #pragma unroll
        for (int r = 0; r < EA_R; ++r) {
            int row = r0 + r;
            if (row < NQA) {
                u16 ne16 = f16bits(-fast_sigmoid(accE[r] + be));   // -e
                u16 a16  = f16bits(fast_tanh(accA[r] + ba));       //  a
                EA[(size_t)row * VD + tid] = (u32)ne16 | ((u32)a16 << 16);
            }
        }
    } else if (blk < EA_B + WQ_B) {
        // ---------------- WQ role (== proven build_wq, 4 q/block) ----------------
        const int lane = tid & 63;
        const int wv   = tid >> 6;
        const int q    = (blk - EA_B) * 4 + wv;
        const bool qok = q < NQ1;
        float* qrow = smem + wv * 64;             // 50 used per wave
        if (qok && lane < KD) qrow[lane] = qemb[q * KD + lane];
        __syncthreads();
        if (!qok) return;

        float s = -1e30f;
        if (lane < MEMN) {
            s = 0.f;
            #pragma unroll
            for (int k = 0; k < KD; ++k) s = fmaf(qrow[k], km[lane * KD + k], s);
        }
        float mx = s;
        #pragma unroll
        for (int off = 32; off >= 1; off >>= 1) mx = fmaxf(mx, __shfl_xor(mx, off, 64));
        float e = (lane < MEMN) ? __expf(s - mx) : 0.f;
        float sum = e;
        #pragma unroll
        for (int off = 32; off >= 1; off >>= 1) sum += __shfl_xor(sum, off, 64);
        float wv_ = (lane < MEMN) ? (e / sum) : 0.f;
        if (lane < MEMN) Wt[q * MEMN + lane] = wv_;

        // f16-pair row: lane i<25 packs (w[2i], w[2i+1])
        float plo = __shfl(wv_, 2 * (lane & 31), 64);
        float phi = __shfl(wv_, 2 * (lane & 31) + 1, 64);
        if (lane < 25) {
            Wh[q * WHS + lane] = (u32)f16bits(plo) | ((u32)f16bits(phi) << 16);
        } else if (lane < WHS) {
            Wh[q * WHS + lane] = 0;
        }

        if (lane < FC) {
            float h = b1[lane];
            #pragma unroll
            for (int k = 0; k < KD; ++k)
                h = fmaf(qrow[k], w1[(VD + k) * FC + lane], h);
            Q1[q * FC + lane] = h;
        }
    } else {
        // ---------------- pack role (== proven pack_w1) ----------------
        for (int idx = (blk - EA_B - WQ_B) * 256 + tid; idx < 4 * 7 * 64 * 8;
             idx += PACK_B * 256) {
            int j    = idx & 7;
            int lane = (idx >> 3) & 63;
            int kt   = (idx >> 9) % 7;
            int nt   = idx / 3584;
            int k = kt * 32 + ((lane >> 4) << 3) + j;
            int n = nt * 16 + (lane & 15);
            float v = (k < VD && n < FC) ? w1[k * FC + n] : 0.f;
            W1s[idx] = f_to_bfu16(v);
        }
    }
}

// ---- recurrence: 256 thr, hfma2 update + fdot2 read, perm EA unpack ----
__global__ __launch_bounds__(256) void dkvmn_state(
        const int* __restrict__ qd, const int* __restrict__ qad,
        const u32* __restrict__ Wh, const u32* __restrict__ EA,
        const float* __restrict__ ivm, u16* __restrict__ READ) {
    const int tid = threadIdx.x;
    const int b   = blockIdx.x;
    const int v   = tid;                         // 0..255, active if < VD
    const bool active = v < VD;
    const int vc = active ? v : VD - 1;

    h2v mv[25];                                  // pair i = slots (2i, 2i+1)
    #pragma unroll
    for (int i = 0; i < 25; ++i) {
        mv[i].x = (_Float16)ivm[(2 * i) * VD + vc];
        mv[i].y = (_Float16)ivm[(2 * i + 1) * VD + vc];
    }

    const int base = b * SS;
    int q_c = __builtin_amdgcn_readfirstlane(qd[base]);
    int q_n = __builtin_amdgcn_readfirstlane(qd[base + 1]);
    int qa0 = __builtin_amdgcn_readfirstlane(qad[base]);
    int qa1 = __builtin_amdgcn_readfirstlane(qad[base + 1]);
    u32 ea_c = EA[(size_t)qa0 * VD + vc];
    u32 ea_n = EA[(size_t)qa1 * VD + vc];

    for (int t = 0; t < SS; ++t) {
        // prefetch step t+2 (clamped index; duplicate load harmless)
        int tn = t + 2; tn = (tn < SS) ? tn : (SS - 1);
        int q_nn  = __builtin_amdgcn_readfirstlane(qd[base + tn]);
        int qa_nn = __builtin_amdgcn_readfirstlane(qad[base + tn]);
        u32 ea_nn = EA[(size_t)qa_nn * VD + vc];

        const u32* wrow = Wh + q_c * WHS;        // uniform -> s_load clause
        // ea_c = {-e (lo f16), a (hi f16)}; broadcast halves via v_perm
        h2v nev2 = u32_to_h2v(__builtin_amdgcn_perm(ea_c, ea_c, 0x01000100u));
        h2v av2  = u32_to_h2v(__builtin_amdgcn_perm(ea_c, ea_c, 0x03020302u));

        float rdA = 0.f, rdB = 0.f;
        #pragma unroll
        for (int i = 0; i < 25; i += 2) {        // 13 iters (i=24 single)
            h2v w0 = u32_to_h2v(wrow[i]);
#if __has_builtin(__builtin_amdgcn_fdot2)
            rdA = __builtin_amdgcn_fdot2(w0, mv[i], rdA, false);
#else
            rdA = fmaf((float)w0.x, (float)mv[i].x,
                  fmaf((float)w0.y, (float)mv[i].y, rdA));
#endif
            mv[i] = __builtin_elementwise_fma(
                w0, __builtin_elementwise_fma(nev2, mv[i], av2), mv[i]);
            if (i + 1 < 25) {
                h2v w1p = u32_to_h2v(wrow[i + 1]);
#if __has_builtin(__builtin_amdgcn_fdot2)
                rdB = __builtin_amdgcn_fdot2(w1p, mv[i + 1], rdB, false);
#else
                rdB = fmaf((float)w1p.x, (float)mv[i + 1].x,
                      fmaf((float)w1p.y, (float)mv[i + 1].y, rdB));
#endif
                mv[i + 1] = __builtin_elementwise_fma(
                    w1p, __builtin_elementwise_fma(nev2, mv[i + 1], av2), mv[i + 1]);
            }
        }
        if (active)
            READ[(size_t)(base + t) * VD + v] = f_to_bfu16(rdA + rdB);
        q_c = q_n; q_n = q_nn; ea_c = ea_n; ea_n = ea_nn;
    }
}

// ---- prediction MLP via MFMA: per wave one 16-row strip, K=224, N=64 ----
__global__ __launch_bounds__(256) void mlp_pred(
        const u16* __restrict__ RD, const int* __restrict__ qd,
        const float* __restrict__ Q1tab, const u16* __restrict__ W1s,
        const float* __restrict__ w2, const float* __restrict__ b2,
        float* __restrict__ out) {
    const int tid  = threadIdx.x;
    const int lane = tid & 63;
    const int wv   = tid >> 6;
    const int strip = blockIdx.x * 4 + wv;
    const int row0  = strip * 16;

    const int mrow = lane & 15;        // A row within strip / C-D col (feature)
    const int quad = lane >> 4;

    s8v a[7];
    {
        const u16* arow = RD + (size_t)(row0 + mrow) * VD + quad * 8;
        #pragma unroll
        for (int kt = 0; kt < 7; ++kt)
            a[kt] = *(const s8v*)(arow + kt * 32);   // k>=200 garbage * B=0
    }

    const float b2f = b2[0];
    float pf[4] = {0.f, 0.f, 0.f, 0.f};

    #pragma unroll
    for (int nt = 0; nt < 4; ++nt) {
        s8v bfr[7];
        #pragma unroll
        for (int kt = 0; kt < 7; ++kt)
            bfr[kt] = *(const s8v*)(W1s + (((nt * 7 + kt) * 64) + lane) * 8);

        f4v acc = {0.f, 0.f, 0.f, 0.f};
        #pragma unroll
        for (int kt = 0; kt < 7; ++kt)
            acc = __builtin_amdgcn_mfma_f32_16x16x32_bf16(a[kt], bfr[kt], acc, 0, 0, 0);

        const int f = nt * 16 + mrow;                  // output feature col
        const float w2f = (f < FC) ? w2[f] : 0.f;
        #pragma unroll
        for (int r = 0; r < 4; ++r) {
            int row = row0 + quad * 4 + r;
            float h = acc[r] + Q1tab[qd[row] * FC + f];
            pf[r] = fmaf(fast_tanh(h), w2f, pf[r]);
        }
    }

    #pragma unroll
    for (int r = 0; r < 4; ++r) {
        float s = pf[r];
        s += __shfl_xor(s, 1, 64);
        s += __shfl_xor(s, 2, 64);
        s += __shfl_xor(s, 4, 64);
        s += __shfl_xor(s, 8, 64);
        if (mrow == 0)
            out[row0 + quad * 4 + r] = fast_sigmoid(s + b2f);
    }
}

// ---- fallback (barrier version, f32) if workspace too small ----
__global__ void dkvmn_main(const int* __restrict__ qd, const int* __restrict__ qad,
                           const float* __restrict__ Wtab, const float* __restrict__ Q1tab,
                           const u32* __restrict__ EA,
                           const float* __restrict__ ivm,
                           const float* __restrict__ w1,
                           const float* __restrict__ w2,
                           const float* __restrict__ b2,
                           float* __restrict__ out) {
    const int tid  = threadIdx.x;
    const int b    = blockIdx.x;
    const int v    = tid;
    const int lane = tid & 63;
    const int wv   = tid >> 6;

    __shared__ alignas(16) float read_lds[4 * 52];
    __shared__ alignas(16) float part_lds[4 * 52];

    float mv[MEMN];
    if (v < VD) {
        #pragma unroll
        for (int m = 0; m < MEMN; ++m) mv[m] = ivm[m * VD + v];
    }
    float w1r[50];
    if (lane < FC) {
        #pragma unroll
        for (int i = 0; i < 50; ++i) w1r[i] = w1[(wv * 50 + i) * FC + lane];
    } else {
        #pragma unroll
        for (int i = 0; i < 50; ++i) w1r[i] = 0.f;
    }
    const float w2f = (tid < FC) ? w2[tid] : 0.f;
    const float b2f = b2[0];

    const int* qrow_i  = qd  + b * SS;
    const int* qarow_i = qad + b * SS;
    const int jchunk = v / 50;
    const int wslot  = jchunk * 52 + (v - jchunk * 50);

    for (int t = 0; t < SS; ++t) {
        const int q  = __builtin_amdgcn_readfirstlane(qrow_i[t]);
        const int qa = __builtin_amdgcn_readfirstlane(qarow_i[t]);
        const float* wrow = Wtab + q * MEMN;

        u32 ea = 0;
        if (v < VD) ea = EA[(size_t)qa * VD + v];
        float ne = h16_to_f((u16)(ea & 0xffffu));   // -e
        float av = h16_to_f((u16)(ea >> 16));       //  a

        if (v < VD) {
            float rd0 = 0.f, rd1 = 0.f;
            #pragma unroll
            for (int m = 0; m < MEMN; m += 2) {
                float wm0 = wrow[m], wm1 = wrow[m + 1];
                rd0 = fmaf(wm0, mv[m], rd0);
                mv[m] = fmaf(wm0, fmaf(ne, mv[m], av), mv[m]);
                rd1 = fmaf(wm1, mv[m + 1], rd1);
                mv[m + 1] = fmaf(wm1, fmaf(ne, mv[m + 1], av), mv[m + 1]);
            }
            read_lds[wslot] = rd0 + rd1;
        }
        __syncthreads();

        float part = 0.f;
        {
            const float* rlc = read_lds + wv * 52;
            #pragma unroll
            for (int i = 0; i < 48; i += 4) {
                float4 x = *(const float4*)(rlc + i);
                part = fmaf(x.x, w1r[i],     part);
                part = fmaf(x.y, w1r[i + 1], part);
                part = fmaf(x.z, w1r[i + 2], part);
                part = fmaf(x.w, w1r[i + 3], part);
            }
            part = fmaf(rlc[48], w1r[48], part);
            part = fmaf(rlc[49], w1r[49], part);
        }
        if (lane < FC) part_lds[wv * 52 + lane] = part;
        __syncthreads();

        if (wv == 0) {
            float pf = 0.f;
            if (lane < FC) {
                float h = part_lds[lane] + part_lds[52 + lane] +
                          part_lds[104 + lane] + part_lds[156 + lane] +
                          Q1tab[q * FC + lane];
                pf = fast_tanh(h) * w2f;
            }
            #pragma unroll
            for (int off = 32; off >= 1; off >>= 1) pf += __shfl_xor(pf, off, 64);
            if (lane == 0) out[b * SS + t] = fast_sigmoid(pf + b2f);
        }
    }
}

extern "C" void kernel_launch(void* const* d_in, const int* in_sizes, int n_in,
                              void* d_out, int out_size, void* d_ws, size_t ws_size,
                              hipStream_t stream) {
    const int* qd  = (const int*)d_in[0];
    const int* qad = (const int*)d_in[1];
    const float* qemb  = (const float*)d_in[2];
    const float* qaemb = (const float*)d_in[3];
    const float* km    = (const float*)d_in[4];
    const float* ivm   = (const float*)d_in[5];
    const float* ew    = (const float*)d_in[6];
    const float* eb    = (const float*)d_in[7];
    const float* aw    = (const float*)d_in[8];
    const float* ab    = (const float*)d_in[9];
    const float* w1    = (const float*)d_in[10];
    const float* b1    = (const float*)d_in[11];
    const float* w2    = (const float*)d_in[12];
    const float* b2    = (const float*)d_in[13];
    float* out = (float*)d_out;
    (void)in_sizes; (void)n_in; (void)out_size;

    char* ws = (char*)d_ws;
    float* Wt  = (float*)(ws);                       // 1,000,200 -> pad 1,000,448
    float* Q1  = (float*)(ws + 1000448);             // 1,000,200 -> pad 1,000,448
    u32*   EA  = (u32*)  (ws + 2000896);             // 8,000,800 -> pad 8,001,024
    u16*   W1s = (u16*)  (ws + 10001920);            // 28,672    -> pad 32,768
    u32*   Wh  = (u32*)  (ws + 10034688);            // 560,112   -> pad 560,640
    u16*   RD  = (u16*)  (ws + 10595328);            // 163,840,000
    const size_t need = 10595328ull + 163840000ull + 512ull;

    // prep: EA + Wt/Wh/Q1 + W1s + zero outputs 1..3 (one dispatch)
    prep<<<PREP_G, 256, 0, stream>>>(qemb, km, w1, b1, qaemb, ew, eb, aw, ab,
                                     Wt, Wh, Q1, EA, W1s, out + (size_t)BB * SS);

    if (ws_size >= need) {
        dkvmn_state<<<BB, 256, 0, stream>>>(qd, qad, Wh, EA, ivm, RD);
        mlp_pred<<<(BB * SS) / 64, 256, 0, stream>>>(RD, qd, Q1, W1s, w2, b2, out);
    } else {
        dkvmn_main<<<BB, 256, 0, stream>>>(qd, qad, Wt, Q1, EA, ivm, w1, w2, b2, out);
    }
}